// Round 1
// baseline (125.906 us; speedup 1.0000x reference)
//
#include <hip/hip_runtime.h>
#include <hip/hip_bf16.h>

#define NR 8192
#define KF 512
#define OF 256

// ws float-offset layout
#define WS_ALPHA 0
#define WS_BETA  8192
#define WS_GAMMA 16384
#define WS_P     24576
#define WS_Q     32768
#define WS_RP    40960   // 512
#define WS_RQ    41472   // 512
#define WS_U     41984   // 256
#define WS_V     42240   // 256
#define WS_BT_BYTES 169984  // 42496 floats * 4 bytes, 16B-aligned

typedef float f32x4 __attribute__((ext_vector_type(4)));
typedef __bf16 bf16x8 __attribute__((ext_vector_type(8)));

// ---------------------------------------------------------------------------
// Kernel A: abs, global sums Sa/Sb, per-row derived scalars; zero accumulators
// ---------------------------------------------------------------------------
__global__ __launch_bounds__(1024) void k_prep(const float* __restrict__ w_s,
                                               const float* __restrict__ w_r,
                                               float* __restrict__ ws) {
    __shared__ float redA[1024];
    __shared__ float redB[1024];
    const int tid = threadIdx.x;
    float a8[8], b8[8];
    float la = 0.f, lb = 0.f;
#pragma unroll
    for (int i = 0; i < 8; ++i) {
        const int idx = tid + (i << 10);
        const float a = fabsf(w_s[idx]);
        const float b = fabsf(w_r[idx]);
        a8[i] = a; b8[i] = b;
        la += a; lb += b;
    }
    redA[tid] = la; redB[tid] = lb;
    __syncthreads();
    for (int s = 512; s > 0; s >>= 1) {
        if (tid < s) { redA[tid] += redA[tid + s]; redB[tid] += redB[tid + s]; }
        __syncthreads();
    }
    const float Sa = redA[0];
    const float Sb = redB[0];
    // zero r_p, r_q, U, V (contiguous 1536 floats)
    for (int z = tid; z < 1536; z += 1024) ws[WS_RP + z] = 0.f;
#pragma unroll
    for (int i = 0; i < 8; ++i) {
        const int idx = tid + (i << 10);
        const float a = a8[i], b = b8[i];
        float s = 0.5f * (a * (Sb - b) + b * (Sa - a));
        if (s == 0.f) s = 1.f;
        const float d = 1.0f / sqrtf(s);
        ws[WS_ALPHA + idx] = 0.5f * d * a;
        ws[WS_BETA  + idx] = 0.5f * d * b;
        ws[WS_GAMMA + idx] = d * d * a * b;
        ws[WS_P     + idx] = d * b;
        ws[WS_Q     + idx] = d * a;
    }
}

// ---------------------------------------------------------------------------
// Kernel W: weight [512][256] f32 -> Bt [256][512] bf16 (transposed)
// ---------------------------------------------------------------------------
__global__ __launch_bounds__(256) void k_wt(const float* __restrict__ weight,
                                            __hip_bfloat16* __restrict__ Bt) {
    const int gid = blockIdx.x * 256 + threadIdx.x;
    for (int e = gid; e < KF * OF; e += 128 * 256) {
        const int k = e >> 8;     // 0..511
        const int c = e & 255;    // 0..255
        Bt[c * KF + k] = __float2bfloat16(weight[e]);
    }
}

// ---------------------------------------------------------------------------
// Kernel B: r_p[m] = sum_j p[j]*input[j][m], r_q likewise (column reduction)
// ---------------------------------------------------------------------------
__global__ __launch_bounds__(256) void k_colred(const float* __restrict__ input,
                                                float* __restrict__ ws) {
    const int tid = threadIdx.x;
    const int c4  = tid & 127;   // column group (4 floats)
    const int rg  = tid >> 7;    // 0/1 row offset
    const int base = blockIdx.x * 32;
    const float* __restrict__ p = ws + WS_P;
    const float* __restrict__ q = ws + WS_Q;
    f32x4 accp = {0.f, 0.f, 0.f, 0.f};
    f32x4 accq = {0.f, 0.f, 0.f, 0.f};
#pragma unroll 4
    for (int r = 0; r < 32; r += 2) {
        const int j = base + r + rg;
        const f32x4 v = *(const f32x4*)(input + j * KF + c4 * 4);
        const float pj = p[j];
        const float qj = q[j];
        accp += pj * v;
        accq += qj * v;
    }
    __shared__ f32x4 lds[256];
    lds[tid] = accp;
    __syncthreads();
    if (tid < 128) {
        f32x4 s = lds[tid] + lds[tid + 128];
#pragma unroll
        for (int i = 0; i < 4; ++i) atomicAdd(ws + WS_RP + c4 * 4 + i, s[i]);
    }
    __syncthreads();
    lds[tid] = accq;
    __syncthreads();
    if (tid < 128) {
        f32x4 s = lds[tid] + lds[tid + 128];
#pragma unroll
        for (int i = 0; i < 4; ++i) atomicAdd(ws + WS_RQ + c4 * 4 + i, s[i]);
    }
}

// ---------------------------------------------------------------------------
// Kernel C: U[k] = sum_m r_p[m]*weight[m][k], V likewise (exact f32)
// ---------------------------------------------------------------------------
__global__ __launch_bounds__(256) void k_uv(const float* __restrict__ weight,
                                            float* __restrict__ ws) {
    const int k  = threadIdx.x;
    const int m0 = blockIdx.x * 32;
    float u = 0.f, v = 0.f;
#pragma unroll 8
    for (int m = m0; m < m0 + 32; ++m) {
        const float wv = weight[m * OF + k];
        u += ws[WS_RP + m] * wv;
        v += ws[WS_RQ + m] * wv;
    }
    atomicAdd(ws + WS_U + k, u);
    atomicAdd(ws + WS_V + k, v);
}

// ---------------------------------------------------------------------------
// Kernel D: H = input@weight via bf16 MFMA (K split over 4 waves), fused
// epilogue out = alpha*U + beta*V - gamma*H
// Block: 256 thr = 4 waves, 16 rows x 256 cols. Grid: 512 blocks.
// ---------------------------------------------------------------------------
__global__ __launch_bounds__(256) void k_out(const float* __restrict__ input,
                                             const __hip_bfloat16* __restrict__ BtH,
                                             const float* __restrict__ ws,
                                             float* __restrict__ out) {
    __shared__ float lds[2][16][256];   // 32 KiB
    const int tid  = threadIdx.x;
    const int w    = tid >> 6;          // wave 0..3 -> K quarter
    const int l    = tid & 63;
    const int r0   = blockIdx.x * 16;
    const int lrow = l & 15;            // MFMA row (A) / col (B)
    const int lkh  = (l >> 4) * 8;      // k sub-offset within K=32 step
    const __bf16* __restrict__ Bt = (const __bf16*)BtH;

    f32x4 acc[16];
#pragma unroll
    for (int nt = 0; nt < 16; ++nt) acc[nt] = (f32x4){0.f, 0.f, 0.f, 0.f};

    const int kb = w * 128;
#pragma unroll
    for (int ks = 0; ks < 4; ++ks) {
        const int k0 = kb + ks * 32 + lkh;
        // A fragment: rows r0..r0+15, 8 consecutive k (f32 -> bf16 in-reg)
        const float* ap = input + (r0 + lrow) * KF + k0;
        const f32x4 alo = *(const f32x4*)ap;
        const f32x4 ahi = *(const f32x4*)(ap + 4);
        bf16x8 af;
        af[0] = (__bf16)alo[0]; af[1] = (__bf16)alo[1];
        af[2] = (__bf16)alo[2]; af[3] = (__bf16)alo[3];
        af[4] = (__bf16)ahi[0]; af[5] = (__bf16)ahi[1];
        af[6] = (__bf16)ahi[2]; af[7] = (__bf16)ahi[3];
#pragma unroll
        for (int nt = 0; nt < 16; ++nt) {
            const bf16x8 bf = *(const bf16x8*)(Bt + (nt * 16 + lrow) * KF + k0);
            acc[nt] = __builtin_amdgcn_mfma_f32_16x16x32_bf16(af, bf, acc[nt], 0, 0, 0);
        }
    }

    // cross-wave K reduction: waves 0,1 write; waves 2,3 add into 0,1
    if (w < 2) {
#pragma unroll
        for (int nt = 0; nt < 16; ++nt)
#pragma unroll
            for (int r = 0; r < 4; ++r)
                lds[w][(l >> 4) * 4 + r][nt * 16 + lrow] = acc[nt][r];
    }
    __syncthreads();
    if (w >= 2) {
#pragma unroll
        for (int nt = 0; nt < 16; ++nt)
#pragma unroll
            for (int r = 0; r < 4; ++r)
                lds[w - 2][(l >> 4) * 4 + r][nt * 16 + lrow] += acc[nt][r];
    }
    __syncthreads();

    // epilogue: out[row][tid] = alpha*U + beta*V - gamma*H
    const float Ut = ws[WS_U + tid];
    const float Vt = ws[WS_V + tid];
#pragma unroll 4
    for (int e = 0; e < 16; ++e) {
        const int row = r0 + e;
        const float h = lds[0][e][tid] + lds[1][e][tid];
        out[row * OF + tid] = ws[WS_ALPHA + row] * Ut
                            + ws[WS_BETA  + row] * Vt
                            - ws[WS_GAMMA + row] * h;
    }
}

// ---------------------------------------------------------------------------
extern "C" void kernel_launch(void* const* d_in, const int* in_sizes, int n_in,
                              void* d_out, int out_size, void* d_ws, size_t ws_size,
                              hipStream_t stream) {
    const float* input  = (const float*)d_in[0];
    const float* w_s    = (const float*)d_in[1];
    const float* w_r    = (const float*)d_in[2];
    const float* weight = (const float*)d_in[3];
    float* ws = (float*)d_ws;
    __hip_bfloat16* Bt = (__hip_bfloat16*)((char*)d_ws + WS_BT_BYTES);
    float* out = (float*)d_out;

    hipLaunchKernelGGL(k_prep,   dim3(1),   dim3(1024), 0, stream, w_s, w_r, ws);
    hipLaunchKernelGGL(k_wt,     dim3(128), dim3(256),  0, stream, weight, Bt);
    hipLaunchKernelGGL(k_colred, dim3(256), dim3(256),  0, stream, input, ws);
    hipLaunchKernelGGL(k_uv,     dim3(16),  dim3(256),  0, stream, weight, ws);
    hipLaunchKernelGGL(k_out,    dim3(512), dim3(256),  0, stream, input, Bt, ws, out);
}

// Round 2
// 101.765 us; speedup vs baseline: 1.2372x; 1.2372x over previous
//
#include <hip/hip_runtime.h>
#include <hip/hip_bf16.h>

#define NR 8192
#define KF 512
#define OF 256

// ws float-offset layout
#define WS_ALPHA  0        // 8192
#define WS_BETA   8192     // 8192
#define WS_GAMMA  16384    // 8192
#define WS_SA     24576    // 2 (Sa, Sb)
#define WS_U      24640    // 256
#define WS_V      24896    // 256
#define WS_PART_P 25152    // 128*512
#define WS_PART_Q 90688    // 128*512
#define WS_BT_BYTES 624896 // (90688+65536)*4, 16B-aligned

typedef float f32x4 __attribute__((ext_vector_type(4)));
typedef __bf16 bf16x8 __attribute__((ext_vector_type(8)));

// ---------------------------------------------------------------------------
// Kernel 1: Sa = sum|w_s|, Sb = sum|w_r| (1 block); zero U/V accumulators
// ---------------------------------------------------------------------------
__global__ __launch_bounds__(1024) void k_sums(const float* __restrict__ w_s,
                                               const float* __restrict__ w_r,
                                               float* __restrict__ ws) {
    __shared__ float redA[1024];
    __shared__ float redB[1024];
    const int tid = threadIdx.x;
    float la = 0.f, lb = 0.f;
#pragma unroll
    for (int i = 0; i < 8; ++i) {
        const int idx = tid + (i << 10);
        la += fabsf(w_s[idx]);
        lb += fabsf(w_r[idx]);
    }
    redA[tid] = la; redB[tid] = lb;
    __syncthreads();
    for (int s = 512; s > 0; s >>= 1) {
        if (tid < s) { redA[tid] += redA[tid + s]; redB[tid] += redB[tid + s]; }
        __syncthreads();
    }
    if (tid == 0) { ws[WS_SA] = redA[0]; ws[WS_SA + 1] = redB[0]; }
    if (tid < 512) ws[WS_U + tid] = 0.f;   // zeros U(256) + V(256)
}

// ---------------------------------------------------------------------------
// Kernel 2: blocks 0..127: per-row scalars + partial column reductions
//           blocks 128..135: weight [512][256] f32 -> Bt [256][512] bf16
// ---------------------------------------------------------------------------
__global__ __launch_bounds__(256) void k_main(const float* __restrict__ input,
                                              const float* __restrict__ w_s,
                                              const float* __restrict__ w_r,
                                              const float* __restrict__ weight,
                                              float* __restrict__ ws,
                                              __hip_bfloat16* __restrict__ Bt) {
    const int tid = threadIdx.x;
    const int blk = blockIdx.x;

    if (blk < 128) {
        // ---- per-row scalars for 64 rows + partial r_p / r_q ----
        __shared__ float pl[64], ql[64];
        __shared__ f32x4 red[256];
        const int base = blk * 64;
        if (tid < 64) {
            const int row = base + tid;
            const float a = fabsf(w_s[row]);
            const float b = fabsf(w_r[row]);
            const float Sa = ws[WS_SA];
            const float Sb = ws[WS_SA + 1];
            float s = 0.5f * (a * (Sb - b) + b * (Sa - a));
            if (s == 0.f) s = 1.f;
            const float d = 1.0f / sqrtf(s);
            ws[WS_ALPHA + row] = 0.5f * d * a;
            ws[WS_BETA  + row] = 0.5f * d * b;
            ws[WS_GAMMA + row] = d * d * a * b;
            pl[tid] = d * b;
            ql[tid] = d * a;
        }
        __syncthreads();
        const int c4 = tid & 127;    // column group of 4 floats
        const int rg = tid >> 7;     // 0/1 -> rows [0,32) / [32,64)
        f32x4 accp = {0.f, 0.f, 0.f, 0.f};
        f32x4 accq = {0.f, 0.f, 0.f, 0.f};
#pragma unroll 8
        for (int r = 0; r < 32; ++r) {
            const int jl = rg * 32 + r;
            const f32x4 v = *(const f32x4*)(input + (base + jl) * KF + c4 * 4);
            accp += pl[jl] * v;
            accq += ql[jl] * v;
        }
        red[tid] = accp;
        __syncthreads();
        if (tid < 128) {
            const f32x4 s = red[tid] + red[tid + 128];
            *(f32x4*)(ws + WS_PART_P + blk * KF + c4 * 4) = s;
        }
        __syncthreads();
        red[tid] = accq;
        __syncthreads();
        if (tid < 128) {
            const f32x4 s = red[tid] + red[tid + 128];
            *(f32x4*)(ws + WS_PART_Q + blk * KF + c4 * 4) = s;
        }
    } else {
        // ---- weight transpose to bf16, LDS-tiled, coalesced both sides ----
        __shared__ float tile[64][65];
        const int tb = blk - 128;          // 0..7
#pragma unroll
        for (int i = 0; i < 4; ++i) {
            const int t  = tb * 4 + i;     // tile 0..31
            const int k0 = (t & 7) * 64;   // 8 k-tiles
            const int c0 = (t >> 3) * 64;  // 4 c-tiles
#pragma unroll
            for (int it = 0; it < 16; ++it) {
                const int idx = it * 256 + tid;
                const int kr = idx >> 6, cc = idx & 63;
                tile[kr][cc] = weight[(k0 + kr) * OF + c0 + cc];
            }
            __syncthreads();
#pragma unroll
            for (int it = 0; it < 16; ++it) {
                const int idx = it * 256 + tid;
                const int cr = idx >> 6, kk = idx & 63;
                Bt[(c0 + cr) * KF + k0 + kk] = __float2bfloat16(tile[kk][cr]);
            }
            __syncthreads();
        }
    }
}

// ---------------------------------------------------------------------------
// Kernel 3: reduce partials -> r_p/r_q slice; U[k] += r_p.W, V[k] += r_q.W
// 16 blocks x 256 threads; only 16-way atomic contention on U/V.
// ---------------------------------------------------------------------------
__global__ __launch_bounds__(256) void k_uv(const float* __restrict__ weight,
                                            float* __restrict__ ws) {
    const int g   = blockIdx.x;     // m-slice [g*32, g*32+32)
    const int tid = threadIdx.x;
    __shared__ float rp[32], rq[32];
    const int m  = tid >> 3;        // 0..31
    const int l8 = tid & 7;
    float sp = 0.f, sq = 0.f;
    for (int b = l8; b < 128; b += 8) {
        sp += ws[WS_PART_P + b * KF + g * 32 + m];
        sq += ws[WS_PART_Q + b * KF + g * 32 + m];
    }
#pragma unroll
    for (int o = 4; o > 0; o >>= 1) {
        sp += __shfl_down(sp, o, 8);
        sq += __shfl_down(sq, o, 8);
    }
    if (l8 == 0) { rp[m] = sp; rq[m] = sq; }
    __syncthreads();
    const int k = tid;
    float u = 0.f, v = 0.f;
#pragma unroll 8
    for (int mm = 0; mm < 32; ++mm) {
        const float wv = weight[(g * 32 + mm) * OF + k];
        u += rp[mm] * wv;
        v += rq[mm] * wv;
    }
    atomicAdd(ws + WS_U + k, u);
    atomicAdd(ws + WS_V + k, v);
}

// ---------------------------------------------------------------------------
// Kernel 4: H = input@weight via bf16 MFMA (K split over 4 waves), fused
// epilogue out = alpha*U + beta*V - gamma*H. 512 blocks x 256 thr.
// ---------------------------------------------------------------------------
__global__ __launch_bounds__(256) void k_out(const float* __restrict__ input,
                                             const __hip_bfloat16* __restrict__ BtH,
                                             const float* __restrict__ ws,
                                             float* __restrict__ out) {
    __shared__ float lds[2][16][256];   // 32 KiB
    const int tid  = threadIdx.x;
    const int w    = tid >> 6;          // wave 0..3 -> K quarter
    const int l    = tid & 63;
    const int r0   = blockIdx.x * 16;
    const int lrow = l & 15;            // MFMA row (A) / col (B)
    const int lkh  = (l >> 4) * 8;      // k sub-offset within K=32 step
    const __bf16* __restrict__ Bt = (const __bf16*)BtH;

    f32x4 acc[16];
#pragma unroll
    for (int nt = 0; nt < 16; ++nt) acc[nt] = (f32x4){0.f, 0.f, 0.f, 0.f};

    const int kb = w * 128;
#pragma unroll
    for (int ks = 0; ks < 4; ++ks) {
        const int k0 = kb + ks * 32 + lkh;
        const float* ap = input + (r0 + lrow) * KF + k0;
        const f32x4 alo = *(const f32x4*)ap;
        const f32x4 ahi = *(const f32x4*)(ap + 4);
        bf16x8 af;
        af[0] = (__bf16)alo[0]; af[1] = (__bf16)alo[1];
        af[2] = (__bf16)alo[2]; af[3] = (__bf16)alo[3];
        af[4] = (__bf16)ahi[0]; af[5] = (__bf16)ahi[1];
        af[6] = (__bf16)ahi[2]; af[7] = (__bf16)ahi[3];
#pragma unroll
        for (int nt = 0; nt < 16; ++nt) {
            const bf16x8 bf = *(const bf16x8*)(Bt + (nt * 16 + lrow) * KF + k0);
            acc[nt] = __builtin_amdgcn_mfma_f32_16x16x32_bf16(af, bf, acc[nt], 0, 0, 0);
        }
    }

    // cross-wave K reduction: waves 0,1 write; waves 2,3 add into 0,1
    if (w < 2) {
#pragma unroll
        for (int nt = 0; nt < 16; ++nt)
#pragma unroll
            for (int r = 0; r < 4; ++r)
                lds[w][(l >> 4) * 4 + r][nt * 16 + lrow] = acc[nt][r];
    }
    __syncthreads();
    if (w >= 2) {
#pragma unroll
        for (int nt = 0; nt < 16; ++nt)
#pragma unroll
            for (int r = 0; r < 4; ++r)
                lds[w - 2][(l >> 4) * 4 + r][nt * 16 + lrow] += acc[nt][r];
    }
    __syncthreads();

    const float Ut = ws[WS_U + tid];
    const float Vt = ws[WS_V + tid];
#pragma unroll 4
    for (int e = 0; e < 16; ++e) {
        const int row = r0 + e;
        const float h = lds[0][e][tid] + lds[1][e][tid];
        out[row * OF + tid] = ws[WS_ALPHA + row] * Ut
                            + ws[WS_BETA  + row] * Vt
                            - ws[WS_GAMMA + row] * h;
    }
}

// ---------------------------------------------------------------------------
extern "C" void kernel_launch(void* const* d_in, const int* in_sizes, int n_in,
                              void* d_out, int out_size, void* d_ws, size_t ws_size,
                              hipStream_t stream) {
    const float* input  = (const float*)d_in[0];
    const float* w_s    = (const float*)d_in[1];
    const float* w_r    = (const float*)d_in[2];
    const float* weight = (const float*)d_in[3];
    float* ws = (float*)d_ws;
    __hip_bfloat16* Bt = (__hip_bfloat16*)((char*)d_ws + WS_BT_BYTES);
    float* out = (float*)d_out;

    hipLaunchKernelGGL(k_sums, dim3(1),   dim3(1024), 0, stream, w_s, w_r, ws);
    hipLaunchKernelGGL(k_main, dim3(136), dim3(256),  0, stream, input, w_s, w_r, weight, ws, Bt);
    hipLaunchKernelGGL(k_uv,   dim3(16),  dim3(256),  0, stream, weight, ws);
    hipLaunchKernelGGL(k_out,  dim3(512), dim3(256),  0, stream, input, Bt, ws, out);
}